// Round 3
// baseline (456.603 us; speedup 1.0000x reference)
//
#include <hip/hip_runtime.h>
#include <hip/hip_bf16.h>
#include <math.h>

// SAM2 MultiScale Block — round 2: ILP/latency fixes on the R1 MFMA version.
// DIM=112(K pad 128), DIM_OUT=224, HEADS=4, HD=56, WS=8, QS=2, MLP=896
//
// ws layout (bytes):
//   hs_bf  @ 0          : 131072x112 bf16 = 29,360,128
//   hs2    @ 29,360,128 : 32768x224 f32   = 29,360,128
//   o_bf   @ 58,720,256 : 32768x224 bf16  = 14,680,064
//   wT     @ 73,400,320 : transposed bf16 weights, 584,192 elems
//     qkvT [672][136] @ +0        rpT [224][136] @ +91392
//     apT  [224][232] @ +121856   m1T [896][232] @ +173824
//     m2T  [224][904] @ +381696

#define SCALE_A 0.13363062095621219f  // 56^-0.5

typedef __attribute__((ext_vector_type(8))) short short8;
typedef __attribute__((ext_vector_type(4))) float f32x4;

__device__ inline short f2bf(float x) {
  union { float f; unsigned u; } v; v.f = x;
  unsigned r = v.u + 0x7fff + ((v.u >> 16) & 1);
  return (short)(r >> 16);
}

// ---------------------------------------------------------------- weight cast
__global__ void cast_w_kernel(const float* __restrict__ qkv_w,
                              const float* __restrict__ rp_w,
                              const float* __restrict__ ap_w,
                              const float* __restrict__ m1_w,
                              const float* __restrict__ m2_w,
                              short* __restrict__ wT) {
  int tid = blockIdx.x * blockDim.x + threadIdx.x;
  int stride = gridDim.x * blockDim.x;
  for (int e = tid; e < 672 * 136; e += stride) {
    int n = e / 136, k = e % 136;
    wT[e] = (k < 112) ? f2bf(qkv_w[k * 672 + n]) : (short)0;
  }
  for (int e = tid; e < 224 * 136; e += stride) {
    int n = e / 136, k = e % 136;
    wT[91392 + e] = (k < 112) ? f2bf(rp_w[k * 224 + n]) : (short)0;
  }
  for (int e = tid; e < 224 * 232; e += stride) {
    int n = e / 232, k = e % 232;
    wT[121856 + e] = (k < 224) ? f2bf(ap_w[k * 224 + n]) : (short)0;
  }
  for (int e = tid; e < 896 * 232; e += stride) {
    int n = e / 232, k = e % 232;
    wT[173824 + e] = (k < 224) ? f2bf(m1_w[k * 896 + n]) : (short)0;
  }
  for (int e = tid; e < 224 * 904; e += stride) {
    int n = e / 904, k = e % 904;
    wT[381696 + e] = (k < 896) ? f2bf(m2_w[k * 224 + n]) : (short)0;
  }
}

// ---------------------------------------------------------------- LN1 -> bf16
__global__ __launch_bounds__(256) void ln1_kernel(
    const float* __restrict__ x, const float* __restrict__ g,
    const float* __restrict__ b, short* __restrict__ hs) {
  int row = blockIdx.x * 4 + (threadIdx.x >> 6);
  int lane = threadIdx.x & 63;
  const float* rp = x + (size_t)row * 112;
  float v0 = rp[lane];
  float v1 = (lane < 48) ? rp[64 + lane] : 0.f;
  float s = v0 + v1;
  #pragma unroll
  for (int off = 32; off; off >>= 1) s += __shfl_down(s, off);
  s = __shfl(s, 0);
  float mean = s * (1.f / 112.f);
  float d0 = v0 - mean;
  float d1 = (lane < 48) ? (v1 - mean) : 0.f;
  float s2 = d0 * d0 + d1 * d1;
  #pragma unroll
  for (int off = 32; off; off >>= 1) s2 += __shfl_down(s2, off);
  s2 = __shfl(s2, 0);
  float rs = rsqrtf(s2 * (1.f / 112.f) + 1e-6f);
  short* op = hs + (size_t)row * 112;
  op[lane] = f2bf(d0 * rs * g[lane] + b[lane]);
  if (lane < 48) op[64 + lane] = f2bf(d1 * rs * g[64 + lane] + b[64 + lane]);
}

// -------------------------------------- res_proj + maxpool2 (MFMA) -> hs2
__global__ __launch_bounds__(256, 4) void respool_kernel(
    const short* __restrict__ hs, const short* __restrict__ rpT,
    const float* __restrict__ bias, float* __restrict__ hs2) {
  __shared__ alignas(16) short w_s[64 * 136];
  int blk = blockIdx.x;  // 2048
  int tid = threadIdx.x;
  for (int e = tid; e < 1024; e += 256) {
    int m = e >> 4, c = e & 15;
    short8* dst = (short8*)&w_s[m * 136 + c * 8];
    if (c < 14) {
      int p = m >> 2, r = m & 3;
      int pix = blk * 16 + p;
      int bb = pix >> 12, ii = (pix >> 6) & 63, jj = pix & 63;
      size_t token = ((size_t)(bb * 128 + 2 * ii + (r >> 1))) * 128 + 2 * jj + (r & 1);
      *dst = *(const short8*)(hs + token * 112 + c * 8);
    } else {
      short8 z = {0, 0, 0, 0, 0, 0, 0, 0};
      *dst = z;
    }
  }
  __syncthreads();
  int wave = tid >> 6, lane = tid & 63, lrow = lane & 15, lq = lane >> 4;
  short8 Ar[4];
  #pragma unroll
  for (int kt = 0; kt < 4; ++kt)
    Ar[kt] = *(const short8*)&w_s[(wave * 16 + lrow) * 136 + kt * 32 + lq * 8];
  int p = wave * 4 + lq;
  for (int pr = 0; pr < 7; ++pr) {
    int c0 = pr * 32 + lrow, c1 = c0 + 16;
    f32x4 acc0 = {0.f, 0.f, 0.f, 0.f}, acc1 = {0.f, 0.f, 0.f, 0.f};
    #pragma unroll
    for (int kt = 0; kt < 4; ++kt) {
      short8 b0 = *(const short8*)(rpT + c0 * 136 + kt * 32 + lq * 8);
      short8 b1 = *(const short8*)(rpT + c1 * 136 + kt * 32 + lq * 8);
      acc0 = __builtin_amdgcn_mfma_f32_16x16x32_bf16(Ar[kt], b0, acc0, 0, 0, 0);
      acc1 = __builtin_amdgcn_mfma_f32_16x16x32_bf16(Ar[kt], b1, acc1, 0, 0, 0);
    }
    float m0 = fmaxf(fmaxf(acc0[0], acc0[1]), fmaxf(acc0[2], acc0[3])) + bias[c0];
    float m1 = fmaxf(fmaxf(acc1[0], acc1[1]), fmaxf(acc1[2], acc1[3])) + bias[c1];
    hs2[(size_t)(blk * 16 + p) * 224 + c0] = m0;
    hs2[(size_t)(blk * 16 + p) * 224 + c1] = m1;
  }
}

// ------------------- fused windowed attention (MFMA qkv / scores / PV)
__global__ __launch_bounds__(256, 3) void attn_kernel(
    const short* __restrict__ hs, const short* __restrict__ qkvT,
    const float* __restrict__ qkv_b, short* __restrict__ o_bf) {
  __shared__ alignas(16) short w_s[64 * 136];   // window tokens, pool order
  __shared__ alignas(16) short k_s[64 * 72];    // keys x hd (cols 56..63 = 0)
  __shared__ alignas(16) short vT_s[64 * 72];   // hd x keys (transposed v)
  __shared__ alignas(16) short q_s[16 * 72];    // pooled q * scale
  __shared__ alignas(16) short p_s[16 * 72];    // softmax(P) bf16
  __shared__ alignas(16) float att[16 * 68];
  int win = blockIdx.x;                         // 2048
  int nw = win & 15, nh = (win >> 4) & 15, b = win >> 8;
  int tid = threadIdx.x;
  int wave = tid >> 6, lane = tid & 63, lrow = lane & 15, lq = lane >> 4;

  for (int e = tid; e < 1024; e += 256) {
    int m = e >> 4, c = e & 15;
    short8* dst = (short8*)&w_s[m * 136 + c * 8];
    if (c < 14) {
      int p = m >> 2, r = m & 3;
      int tr = (p >> 2) * 2 + (r >> 1), tc = (p & 3) * 2 + (r & 1);
      size_t token = ((size_t)(b * 128 + nh * 8 + tr)) * 128 + (nw * 8 + tc);
      *dst = *(const short8*)(hs + token * 112 + c * 8);
    } else {
      short8 z = {0, 0, 0, 0, 0, 0, 0, 0};
      *dst = z;
    }
  }
  for (int e = tid; e < 512; e += 256) k_s[(e >> 3) * 72 + 56 + (e & 7)] = 0;
  if (tid < 128) q_s[(tid >> 3) * 72 + 56 + (tid & 7)] = 0;
  __syncthreads();

  short8 Aq[4];
  #pragma unroll
  for (int kt = 0; kt < 4; ++kt)
    Aq[kt] = *(const short8*)&w_s[(wave * 16 + lrow) * 136 + kt * 32 + lq * 8];

#define QKV_EPI(CL, ACC) {                                                \
    int cl_ = (CL);                                                       \
    if (cl_ < 168) {                                                      \
      int bcol_ = (cl_ < 56) ? (h * 56 + cl_)                             \
                : (cl_ < 112) ? (224 + h * 56 + (cl_ - 56))               \
                              : (448 + h * 56 + (cl_ - 112));             \
      float bias_ = qkv_b[bcol_];                                         \
      if (cl_ < 56) {                                                     \
        float mx_ = fmaxf(fmaxf((ACC)[0], (ACC)[1]),                      \
                          fmaxf((ACC)[2], (ACC)[3])) + bias_;             \
        q_s[(wave * 4 + lq) * 72 + cl_] = f2bf(mx_ * SCALE_A);            \
      } else if (cl_ < 112) {                                             \
        _Pragma("unroll")                                                 \
        for (int r_ = 0; r_ < 4; ++r_)                                    \
          k_s[(wave * 16 + lq * 4 + r_) * 72 + (cl_ - 56)] =              \
              f2bf((ACC)[r_] + bias_);                                    \
      } else {                                                            \
        _Pragma("unroll")                                                 \
        for (int r_ = 0; r_ < 4; ++r_)                                    \
          vT_s[(cl_ - 112) * 72 + wave * 16 + lq * 4 + r_] =              \
              f2bf((ACC)[r_] + bias_);                                    \
      }                                                                   \
    }                                                                     \
  }

  for (int h = 0; h < 4; ++h) {
    // qkv projection: 11 N-tiles, paired (5 pairs + 1 single)
    for (int pr = 0; pr < 5; ++pr) {
      int cl0 = pr * 32 + lrow, cl1 = cl0 + 16;
      int bc0 = (cl0 < 56) ? (h * 56 + cl0)
              : (cl0 < 112) ? (224 + h * 56 + (cl0 - 56))
                            : (448 + h * 56 + (cl0 - 112));
      int bc1 = (cl1 < 56) ? (h * 56 + cl1)
              : (cl1 < 112) ? (224 + h * 56 + (cl1 - 56))
                            : (448 + h * 56 + (cl1 - 112));
      f32x4 acc0 = {0.f, 0.f, 0.f, 0.f}, acc1 = {0.f, 0.f, 0.f, 0.f};
      #pragma unroll
      for (int kt = 0; kt < 4; ++kt) {
        short8 b0 = *(const short8*)(qkvT + bc0 * 136 + kt * 32 + lq * 8);
        short8 b1 = *(const short8*)(qkvT + bc1 * 136 + kt * 32 + lq * 8);
        acc0 = __builtin_amdgcn_mfma_f32_16x16x32_bf16(Aq[kt], b0, acc0, 0, 0, 0);
        acc1 = __builtin_amdgcn_mfma_f32_16x16x32_bf16(Aq[kt], b1, acc1, 0, 0, 0);
      }
      QKV_EPI(cl0, acc0);
      QKV_EPI(cl1, acc1);
    }
    {
      int cl = 160 + lrow;
      int bc = (cl < 168) ? (448 + h * 56 + (cl - 112)) : (448 + h * 56 + 55);
      f32x4 acc = {0.f, 0.f, 0.f, 0.f};
      #pragma unroll
      for (int kt = 0; kt < 4; ++kt) {
        short8 bf = *(const short8*)(qkvT + bc * 136 + kt * 32 + lq * 8);
        acc = __builtin_amdgcn_mfma_f32_16x16x32_bf16(Aq[kt], bf, acc, 0, 0, 0);
      }
      QKV_EPI(cl, acc);
    }
    __syncthreads();
    // scores: wave handles keys [wave*16, +16)
    {
      f32x4 acc = {0.f, 0.f, 0.f, 0.f};
      #pragma unroll
      for (int kt = 0; kt < 2; ++kt) {
        short8 a = *(const short8*)&q_s[lrow * 72 + kt * 32 + lq * 8];
        short8 bf = *(const short8*)&k_s[(wave * 16 + lrow) * 72 + kt * 32 + lq * 8];
        acc = __builtin_amdgcn_mfma_f32_16x16x32_bf16(a, bf, acc, 0, 0, 0);
      }
      #pragma unroll
      for (int r = 0; r < 4; ++r)
        att[(lq * 4 + r) * 68 + wave * 16 + lrow] = acc[r];
    }
    __syncthreads();
    // softmax: 256 threads, 16 lanes per row, normalized bf16 P
    {
      int row = tid >> 4, l = tid & 15;
      float v0 = att[row * 68 + l];
      float v1 = att[row * 68 + l + 16];
      float v2 = att[row * 68 + l + 32];
      float v3 = att[row * 68 + l + 48];
      float m = fmaxf(fmaxf(v0, v1), fmaxf(v2, v3));
      #pragma unroll
      for (int off = 8; off; off >>= 1) m = fmaxf(m, __shfl_xor(m, off, 16));
      float e0 = __expf(v0 - m), e1 = __expf(v1 - m);
      float e2 = __expf(v2 - m), e3 = __expf(v3 - m);
      float s = e0 + e1 + e2 + e3;
      #pragma unroll
      for (int off = 8; off; off >>= 1) s += __shfl_xor(s, off, 16);
      float inv = 1.f / s;
      p_s[row * 72 + l]      = f2bf(e0 * inv);
      p_s[row * 72 + l + 16] = f2bf(e1 * inv);
      p_s[row * 72 + l + 32] = f2bf(e2 * inv);
      p_s[row * 72 + l + 48] = f2bf(e3 * inv);
    }
    __syncthreads();
    // PV: wave handles out cols [wave*16, +16)
    {
      int col = wave * 16 + lrow;
      f32x4 acc = {0.f, 0.f, 0.f, 0.f};
      #pragma unroll
      for (int kt = 0; kt < 2; ++kt) {
        short8 a = *(const short8*)&p_s[lrow * 72 + kt * 32 + lq * 8];
        short8 bf = *(const short8*)&vT_s[col * 72 + kt * 32 + lq * 8];
        acc = __builtin_amdgcn_mfma_f32_16x16x32_bf16(a, bf, acc, 0, 0, 0);
      }
      if (col < 56) {
        #pragma unroll
        for (int r = 0; r < 4; ++r) {
          int p = lq * 4 + r;
          size_t token = ((size_t)(b * 64 + nh * 4 + (p >> 2))) * 64 + (nw * 4 + (p & 3));
          o_bf[token * 224 + h * 56 + col] = f2bf(acc[r]);
        }
      }
    }
    __syncthreads();
  }
#undef QKV_EPI
}

// ---------------------------- attn_proj GEMM + bias + residual into hs2
__global__ __launch_bounds__(256, 4) void aproj_kernel(
    const short* __restrict__ o_bf, const short* __restrict__ apT,
    const float* __restrict__ apb, float* __restrict__ hs2) {
  __shared__ alignas(16) short o_s[64 * 232];
  int blk = blockIdx.x;  // 512 x 64 tokens
  int tid = threadIdx.x;
  for (int e = tid; e < 64 * 28; e += 256) {
    int m = e / 28, c = e % 28;
    *(short8*)&o_s[m * 232 + c * 8] =
        *(const short8*)(o_bf + ((size_t)blk * 64 + m) * 224 + c * 8);
  }
  __syncthreads();
  int wave = tid >> 6, lane = tid & 63, lrow = lane & 15, lq = lane >> 4;
  short8 Ao[7];
  #pragma unroll
  for (int kt = 0; kt < 7; ++kt)
    Ao[kt] = *(const short8*)&o_s[(wave * 16 + lrow) * 232 + kt * 32 + lq * 8];
  for (int pr = 0; pr < 7; ++pr) {
    int c0 = pr * 32 + lrow, c1 = c0 + 16;
    f32x4 acc0 = {0.f, 0.f, 0.f, 0.f}, acc1 = {0.f, 0.f, 0.f, 0.f};
    #pragma unroll
    for (int kt = 0; kt < 7; ++kt) {
      short8 b0 = *(const short8*)(apT + c0 * 232 + kt * 32 + lq * 8);
      short8 b1 = *(const short8*)(apT + c1 * 232 + kt * 32 + lq * 8);
      acc0 = __builtin_amdgcn_mfma_f32_16x16x32_bf16(Ao[kt], b0, acc0, 0, 0, 0);
      acc1 = __builtin_amdgcn_mfma_f32_16x16x32_bf16(Ao[kt], b1, acc1, 0, 0, 0);
    }
    float bi0 = apb[c0], bi1 = apb[c1];
    #pragma unroll
    for (int r = 0; r < 4; ++r) {
      size_t row = (size_t)blk * 64 + wave * 16 + lq * 4 + r;
      hs2[row * 224 + c0] += acc0[r] + bi0;
      hs2[row * 224 + c1] += acc1[r] + bi1;
    }
  }
}

// ------------- fused LN2 + mlp1(MFMA) + GELU + mlp2(MFMA) + residual
// 32 tokens/block; waves own an N-range and compute BOTH 16-row M-tiles
// (B-frags reused across M, 4 independent MFMA chains).
__global__ __launch_bounds__(256, 2) void mlp_kernel(
    const float* __restrict__ hs2, const float* __restrict__ g2,
    const float* __restrict__ b2, const short* __restrict__ m1T,
    const float* __restrict__ b1, const short* __restrict__ m2T,
    const float* __restrict__ b2b, float* __restrict__ out) {
  __shared__ alignas(16) short ln_s[32 * 232];
  __shared__ alignas(16) short hid_s[32 * 904];
  __shared__ float red[32][2];
  int blk = blockIdx.x;  // 1024 x 32 tokens
  int tid = threadIdx.x;
  size_t base = (size_t)blk * 32 * 224;
  {
    int row = tid >> 3, l8 = tid & 7;
    const float* rp = hs2 + base + (size_t)row * 224;
    float s = 0.f;
    for (int c = l8; c < 224; c += 8) s += rp[c];
    #pragma unroll
    for (int off = 4; off; off >>= 1) s += __shfl_xor(s, off, 8);
    float mean = s * (1.f / 224.f);
    float s2 = 0.f;
    for (int c = l8; c < 224; c += 8) { float d = rp[c] - mean; s2 = fmaf(d, d, s2); }
    #pragma unroll
    for (int off = 4; off; off >>= 1) s2 += __shfl_xor(s2, off, 8);
    if (l8 == 0) { red[row][0] = mean; red[row][1] = rsqrtf(s2 * (1.f / 224.f) + 1e-6f); }
  }
  __syncthreads();
  for (int e = tid; e < 32 * 224; e += 256) {
    int m = e / 224, c = e % 224;
    float v = hs2[base + (size_t)m * 224 + c];
    ln_s[m * 232 + c] = f2bf((v - red[m][0]) * red[m][1] * g2[c] + b2[c]);
  }
  __syncthreads();
  int wave = tid >> 6, lane = tid & 63, lrow = lane & 15, lq = lane >> 4;
  // hoisted A-frags: 2 M-tiles x 7 k-tiles
  short8 A[2][7];
  #pragma unroll
  for (int mt = 0; mt < 2; ++mt)
    #pragma unroll
    for (int kt = 0; kt < 7; ++kt)
      A[mt][kt] = *(const short8*)&ln_s[(mt * 16 + lrow) * 232 + kt * 32 + lq * 8];
  // GEMM1: wave owns N-tiles [wave*14, wave*14+14), processed in pairs
  for (int p = 0; p < 7; ++p) {
    int c0 = (wave * 14 + 2 * p) * 16 + lrow, c1 = c0 + 16;
    f32x4 a00 = {0.f, 0.f, 0.f, 0.f}, a01 = a00, a10 = a00, a11 = a00;
    #pragma unroll
    for (int kt = 0; kt < 7; ++kt) {
      short8 b0 = *(const short8*)(m1T + c0 * 232 + kt * 32 + lq * 8);
      short8 b1 = *(const short8*)(m1T + c1 * 232 + kt * 32 + lq * 8);
      a00 = __builtin_amdgcn_mfma_f32_16x16x32_bf16(A[0][kt], b0, a00, 0, 0, 0);
      a10 = __builtin_amdgcn_mfma_f32_16x16x32_bf16(A[1][kt], b0, a10, 0, 0, 0);
      a01 = __builtin_amdgcn_mfma_f32_16x16x32_bf16(A[0][kt], b1, a01, 0, 0, 0);
      a11 = __builtin_amdgcn_mfma_f32_16x16x32_bf16(A[1][kt], b1, a11, 0, 0, 0);
    }
    float bi0 = b1[c0], bi1 = b1[c1];
    #pragma unroll
    for (int r = 0; r < 4; ++r) {
      float x00 = a00[r] + bi0, x01 = a01[r] + bi1;
      float x10 = a10[r] + bi0, x11 = a11[r] + bi1;
      hid_s[(lq * 4 + r) * 904 + c0]      = f2bf(0.5f * x00 * (1.f + erff(x00 * 0.70710678118f)));
      hid_s[(lq * 4 + r) * 904 + c1]      = f2bf(0.5f * x01 * (1.f + erff(x01 * 0.70710678118f)));
      hid_s[(16 + lq * 4 + r) * 904 + c0] = f2bf(0.5f * x10 * (1.f + erff(x10 * 0.70710678118f)));
      hid_s[(16 + lq * 4 + r) * 904 + c1] = f2bf(0.5f * x11 * (1.f + erff(x11 * 0.70710678118f)));
    }
  }
  __syncthreads();
  // GEMM2: 7 N-tile pairs over 4 waves (waves 0..2 get 2, wave 3 gets 1)
  for (int pp = wave; pp < 7; pp += 4) {
    int c0 = (2 * pp) * 16 + lrow, c1 = c0 + 16;
    f32x4 a00 = {0.f, 0.f, 0.f, 0.f}, a01 = a00, a10 = a00, a11 = a00;
    #pragma unroll
    for (int kt = 0; kt < 28; ++kt) {
      short8 x0 = *(const short8*)&hid_s[lrow * 904 + kt * 32 + lq * 8];
      short8 x1 = *(const short8*)&hid_s[(16 + lrow) * 904 + kt * 32 + lq * 8];
      short8 b0 = *(const short8*)(m2T + c0 * 904 + kt * 32 + lq * 8);
      short8 b1 = *(const short8*)(m2T + c1 * 904 + kt * 32 + lq * 8);
      a00 = __builtin_amdgcn_mfma_f32_16x16x32_bf16(x0, b0, a00, 0, 0, 0);
      a10 = __builtin_amdgcn_mfma_f32_16x16x32_bf16(x1, b0, a10, 0, 0, 0);
      a01 = __builtin_amdgcn_mfma_f32_16x16x32_bf16(x0, b1, a01, 0, 0, 0);
      a11 = __builtin_amdgcn_mfma_f32_16x16x32_bf16(x1, b1, a11, 0, 0, 0);
    }
    float bi0 = b2b[c0], bi1 = b2b[c1];
    #pragma unroll
    for (int r = 0; r < 4; ++r) {
      size_t i00 = base + (size_t)(lq * 4 + r) * 224 + c0;
      size_t i01 = base + (size_t)(lq * 4 + r) * 224 + c1;
      size_t i10 = base + (size_t)(16 + lq * 4 + r) * 224 + c0;
      size_t i11 = base + (size_t)(16 + lq * 4 + r) * 224 + c1;
      out[i00] = hs2[i00] + a00[r] + bi0;
      out[i01] = hs2[i01] + a01[r] + bi1;
      out[i10] = hs2[i10] + a10[r] + bi0;
      out[i11] = hs2[i11] + a11[r] + bi1;
    }
  }
}

extern "C" void kernel_launch(void* const* d_in, const int* in_sizes, int n_in,
                              void* d_out, int out_size, void* d_ws, size_t ws_size,
                              hipStream_t stream) {
  const float* x    = (const float*)d_in[0];
  const float* ln1g = (const float*)d_in[1];
  const float* ln1b = (const float*)d_in[2];
  const float* qkvw = (const float*)d_in[3];
  const float* qkvb = (const float*)d_in[4];
  const float* apw  = (const float*)d_in[5];
  const float* apb  = (const float*)d_in[6];
  const float* rpw  = (const float*)d_in[7];
  const float* rpb  = (const float*)d_in[8];
  const float* ln2g = (const float*)d_in[9];
  const float* ln2b = (const float*)d_in[10];
  const float* w1   = (const float*)d_in[11];
  const float* b1   = (const float*)d_in[12];
  const float* w2   = (const float*)d_in[13];
  const float* b2   = (const float*)d_in[14];
  float* out = (float*)d_out;

  short* hs_bf = (short*)d_ws;
  float* hs2   = (float*)((char*)d_ws + 29360128);
  short* o_bf  = (short*)((char*)d_ws + 58720256);
  short* wT    = (short*)((char*)d_ws + 73400320);

  cast_w_kernel<<<1024, 256, 0, stream>>>(qkvw, rpw, apw, w1, w2, wT);
  ln1_kernel<<<32768, 256, 0, stream>>>(x, ln1g, ln1b, hs_bf);
  respool_kernel<<<2048, 256, 0, stream>>>(hs_bf, wT + 91392, rpb, hs2);
  attn_kernel<<<2048, 256, 0, stream>>>(hs_bf, wT, qkvb, o_bf);
  aproj_kernel<<<512, 256, 0, stream>>>(o_bf, wT + 121856, apb, hs2);
  mlp_kernel<<<1024, 256, 0, stream>>>(hs2, ln2g, ln2b, wT + 173824, b1,
                                       wT + 381696, b2, out);
}

// Round 4
// 312.194 us; speedup vs baseline: 1.4626x; 1.4626x over previous
//
#include <hip/hip_runtime.h>
#include <hip/hip_bf16.h>
#include <math.h>

// SAM2 MultiScale Block — round 3: occupancy + frag-order weight packing.
// DIM=112(K pad 128), DIM_OUT=224, HEADS=4, HD=56, WS=8, QS=2, MLP=896
//
// ws layout (bytes):
//   hs_bf @ 0          : 131072x112 bf16 = 29,360,128
//   hs2   @ 29,360,128 : 32768x224 f32   = 29,360,128
//   o_bf  @ 58,720,256 : 32768x224 bf16  = 14,680,064
//   wF    @ 73,400,320 : frag-packed bf16 weights (elems):
//     qkvF 704x128 @ +0       rpF 224x128 @ +90112   apF 224x224 @ +118784
//     m1F  896x224 @ +168960  m2F 224x896 @ +369664  (end 570368)
// Frag order: elem (n,k) -> tile=(n/16)*KT+(k/32); flat=(tile*64+lane)*8+j
//   with lane=((k%32)/8)*16+(n%16), j=k%8  => one wave B-frag = 1KB contiguous.

#define SCALE_A 0.13363062095621219f  // 56^-0.5

typedef __attribute__((ext_vector_type(8))) short short8;
typedef __attribute__((ext_vector_type(4))) float f32x4;

__device__ inline short f2bf(float x) {
  union { float f; unsigned u; } v; v.f = x;
  unsigned r = v.u + 0x7fff + ((v.u >> 16) & 1);
  return (short)(r >> 16);
}
__device__ inline float gelu_exact(float x) {
  return 0.5f * x * (1.f + erff(x * 0.70710678118f));
}

// ------------------------------------------- weight cast to frag order
__global__ void cast_w_kernel(const float* __restrict__ qkv_w,
                              const float* __restrict__ rp_w,
                              const float* __restrict__ ap_w,
                              const float* __restrict__ m1_w,
                              const float* __restrict__ m2_w,
                              short* __restrict__ wF) {
  int tid = blockIdx.x * blockDim.x + threadIdx.x;
  int stride = gridDim.x * blockDim.x;
  // qkvF: permuted cols cp = h*176 + cl; cl: [q 0..55|k 56..111|v 112..167|pad]
  for (int e = tid; e < 90112; e += stride) {
    int j = e & 7, lr = (e >> 3) & 15, lqq = (e >> 7) & 3, tile = e >> 9;
    int kt = tile & 3, nt = tile >> 2;
    int cp = nt * 16 + lr;
    int h = cp / 176, cl = cp % 176;
    int k = kt * 32 + lqq * 8 + j;
    float val = 0.f;
    if (k < 112 && cl < 168) {
      int bcol = (cl < 56) ? (h * 56 + cl)
               : (cl < 112) ? (224 + h * 56 + (cl - 56))
                            : (448 + h * 56 + (cl - 112));
      val = qkv_w[k * 672 + bcol];
    }
    wF[e] = f2bf(val);
  }
  for (int e = tid; e < 28672; e += stride) {  // rpF: N=224, KT=4
    int j = e & 7, lr = (e >> 3) & 15, lqq = (e >> 7) & 3, tile = e >> 9;
    int kt = tile & 3, nt = tile >> 2;
    int n = nt * 16 + lr, k = kt * 32 + lqq * 8 + j;
    wF[90112 + e] = (k < 112) ? f2bf(rp_w[k * 224 + n]) : (short)0;
  }
  for (int e = tid; e < 50176; e += stride) {  // apF: N=224, KT=7
    int j = e & 7, lr = (e >> 3) & 15, lqq = (e >> 7) & 3, tile = e >> 9;
    int kt = tile % 7, nt = tile / 7;
    int n = nt * 16 + lr, k = kt * 32 + lqq * 8 + j;
    wF[118784 + e] = f2bf(ap_w[k * 224 + n]);
  }
  for (int e = tid; e < 200704; e += stride) {  // m1F: N=896, KT=7
    int j = e & 7, lr = (e >> 3) & 15, lqq = (e >> 7) & 3, tile = e >> 9;
    int kt = tile % 7, nt = tile / 7;
    int n = nt * 16 + lr, k = kt * 32 + lqq * 8 + j;
    wF[168960 + e] = f2bf(m1_w[k * 896 + n]);
  }
  for (int e = tid; e < 200704; e += stride) {  // m2F: N=224, KT=28
    int j = e & 7, lr = (e >> 3) & 15, lqq = (e >> 7) & 3, tile = e >> 9;
    int kt = tile % 28, nt = tile / 28;
    int n = nt * 16 + lr, k = kt * 32 + lqq * 8 + j;
    wF[369664 + e] = f2bf(m2_w[k * 224 + n]);
  }
}

// ---------------------------------------------------------------- LN1 -> bf16
__global__ __launch_bounds__(256) void ln1_kernel(
    const float* __restrict__ x, const float* __restrict__ g,
    const float* __restrict__ b, short* __restrict__ hs) {
  int row = blockIdx.x * 4 + (threadIdx.x >> 6);
  int lane = threadIdx.x & 63;
  const float* rp = x + (size_t)row * 112;
  float v0 = rp[lane];
  float v1 = (lane < 48) ? rp[64 + lane] : 0.f;
  float s = v0 + v1;
  #pragma unroll
  for (int off = 32; off; off >>= 1) s += __shfl_down(s, off);
  s = __shfl(s, 0);
  float mean = s * (1.f / 112.f);
  float d0 = v0 - mean;
  float d1 = (lane < 48) ? (v1 - mean) : 0.f;
  float s2 = d0 * d0 + d1 * d1;
  #pragma unroll
  for (int off = 32; off; off >>= 1) s2 += __shfl_down(s2, off);
  s2 = __shfl(s2, 0);
  float rs = rsqrtf(s2 * (1.f / 112.f) + 1e-6f);
  short* op = hs + (size_t)row * 112;
  op[lane] = f2bf(d0 * rs * g[lane] + b[lane]);
  if (lane < 48) op[64 + lane] = f2bf(d1 * rs * g[64 + lane] + b[64 + lane]);
}

// -------------------------------------- res_proj + maxpool2 (MFMA) -> hs2
__global__ __launch_bounds__(256, 4) void respool_kernel(
    const short* __restrict__ hs, const short* __restrict__ rpF,
    const float* __restrict__ bias, float* __restrict__ hs2) {
  __shared__ alignas(16) short w_s[64 * 136];
  int blk = blockIdx.x;  // 2048
  int tid = threadIdx.x;
  for (int e = tid; e < 1024; e += 256) {
    int m = e >> 4, c = e & 15;
    short8* dst = (short8*)&w_s[m * 136 + c * 8];
    if (c < 14) {
      int p = m >> 2, r = m & 3;
      int pix = blk * 16 + p;
      int bb = pix >> 12, ii = (pix >> 6) & 63, jj = pix & 63;
      size_t token = ((size_t)(bb * 128 + 2 * ii + (r >> 1))) * 128 + 2 * jj + (r & 1);
      *dst = *(const short8*)(hs + token * 112 + c * 8);
    } else {
      short8 z = {0, 0, 0, 0, 0, 0, 0, 0};
      *dst = z;
    }
  }
  __syncthreads();
  int wave = tid >> 6, lane = tid & 63, lrow = lane & 15, lq = lane >> 4;
  short8 Ar[4];
  #pragma unroll
  for (int kt = 0; kt < 4; ++kt)
    Ar[kt] = *(const short8*)&w_s[(wave * 16 + lrow) * 136 + kt * 32 + lq * 8];
  int p = wave * 4 + lq;
  for (int pr = 0; pr < 7; ++pr) {
    int c0 = pr * 32 + lrow, c1 = c0 + 16;
    f32x4 acc0 = {0.f, 0.f, 0.f, 0.f}, acc1 = {0.f, 0.f, 0.f, 0.f};
    #pragma unroll
    for (int kt = 0; kt < 4; ++kt) {
      short8 b0 = *(const short8*)(rpF + (((2 * pr) * 4 + kt) * 64 + lane) * 8);
      short8 b1 = *(const short8*)(rpF + (((2 * pr + 1) * 4 + kt) * 64 + lane) * 8);
      acc0 = __builtin_amdgcn_mfma_f32_16x16x32_bf16(Ar[kt], b0, acc0, 0, 0, 0);
      acc1 = __builtin_amdgcn_mfma_f32_16x16x32_bf16(Ar[kt], b1, acc1, 0, 0, 0);
    }
    float m0 = fmaxf(fmaxf(acc0[0], acc0[1]), fmaxf(acc0[2], acc0[3])) + bias[c0];
    float m1 = fmaxf(fmaxf(acc1[0], acc1[1]), fmaxf(acc1[2], acc1[3])) + bias[c1];
    hs2[(size_t)(blk * 16 + p) * 224 + c0] = m0;
    hs2[(size_t)(blk * 16 + p) * 224 + c1] = m1;
  }
}

// ------------------- fused windowed attention, 4 blocks/CU
__global__ __launch_bounds__(256, 4) void attn_kernel(
    const short* __restrict__ hs, const short* __restrict__ qkvF,
    const float* __restrict__ qkv_b, short* __restrict__ o_bf) {
  __shared__ alignas(16) short w_s[64 * 136];   // 17408 B
  __shared__ alignas(16) short kp_s[64 * 72];   //  9216 B (k; p overlays rows 0..15)
  __shared__ alignas(16) short vT_s[64 * 72];   //  9216 B
  __shared__ alignas(16) short q_s[16 * 72];    //  2304 B
  __shared__ float pm_s[16][4];                 //   256 B
  __shared__ float ps_s[16][4];                 //   256 B  => 38656 B total
  int win = blockIdx.x;                         // 2048
  int nw = win & 15, nh = (win >> 4) & 15, b = win >> 8;
  int tid = threadIdx.x;
  int wave = tid >> 6, lane = tid & 63, lrow = lane & 15, lq = lane >> 4;

  for (int e = tid; e < 1024; e += 256) {
    int m = e >> 4, c = e & 15;
    short8* dst = (short8*)&w_s[m * 136 + c * 8];
    if (c < 14) {
      int p = m >> 2, r = m & 3;
      int tr = (p >> 2) * 2 + (r >> 1), tc = (p & 3) * 2 + (r & 1);
      size_t token = ((size_t)(b * 128 + nh * 8 + tr)) * 128 + (nw * 8 + tc);
      *dst = *(const short8*)(hs + token * 112 + c * 8);
    } else {
      short8 z = {0, 0, 0, 0, 0, 0, 0, 0};
      *dst = z;
    }
  }
  for (int e = tid; e < 512; e += 256) kp_s[(e >> 3) * 72 + 56 + (e & 7)] = 0;
  if (tid < 128) q_s[(tid >> 3) * 72 + 56 + (tid & 7)] = 0;
  __syncthreads();

  short8 Aq[4];
  #pragma unroll
  for (int kt = 0; kt < 4; ++kt)
    Aq[kt] = *(const short8*)&w_s[(wave * 16 + lrow) * 136 + kt * 32 + lq * 8];

#define QKV_EPI(CL, ACC) {                                                \
    int cl_ = (CL);                                                       \
    if (cl_ < 168) {                                                      \
      int bcol_ = (cl_ < 56) ? (h * 56 + cl_)                             \
                : (cl_ < 112) ? (224 + h * 56 + (cl_ - 56))               \
                              : (448 + h * 56 + (cl_ - 112));             \
      float bias_ = qkv_b[bcol_];                                         \
      if (cl_ < 56) {                                                     \
        float mx_ = fmaxf(fmaxf((ACC)[0], (ACC)[1]),                      \
                          fmaxf((ACC)[2], (ACC)[3])) + bias_;             \
        q_s[(wave * 4 + lq) * 72 + cl_] = f2bf(mx_ * SCALE_A);            \
      } else if (cl_ < 112) {                                             \
        _Pragma("unroll")                                                 \
        for (int r_ = 0; r_ < 4; ++r_)                                    \
          kp_s[(wave * 16 + lq * 4 + r_) * 72 + (cl_ - 56)] =             \
              f2bf((ACC)[r_] + bias_);                                    \
      } else {                                                            \
        _Pragma("unroll")                                                 \
        for (int r_ = 0; r_ < 4; ++r_)                                    \
          vT_s[(cl_ - 112) * 72 + wave * 16 + lq * 4 + r_] =              \
              f2bf((ACC)[r_] + bias_);                                    \
      }                                                                   \
    }                                                                     \
  }

  for (int h = 0; h < 4; ++h) {
    // restore zero-pad in kp rows 0..15 cols 56..63 (clobbered by prev P)
    if (h && tid < 128) kp_s[(tid >> 3) * 72 + 56 + (tid & 7)] = 0;
    // qkv: 11 N-tiles (head-permuted frag layout), 5 pairs + 1
    for (int pr = 0; pr < 5; ++pr) {
      int t0 = 2 * pr, t1 = t0 + 1;
      int cl0 = t0 * 16 + lrow, cl1 = cl0 + 16;
      f32x4 acc0 = {0.f, 0.f, 0.f, 0.f}, acc1 = {0.f, 0.f, 0.f, 0.f};
      #pragma unroll
      for (int kt = 0; kt < 4; ++kt) {
        short8 b0 = *(const short8*)(qkvF + (((h * 11 + t0) * 4 + kt) * 64 + lane) * 8);
        short8 b1 = *(const short8*)(qkvF + (((h * 11 + t1) * 4 + kt) * 64 + lane) * 8);
        acc0 = __builtin_amdgcn_mfma_f32_16x16x32_bf16(Aq[kt], b0, acc0, 0, 0, 0);
        acc1 = __builtin_amdgcn_mfma_f32_16x16x32_bf16(Aq[kt], b1, acc1, 0, 0, 0);
      }
      QKV_EPI(cl0, acc0);
      QKV_EPI(cl1, acc1);
    }
    {
      int cl = 160 + lrow;
      f32x4 acc = {0.f, 0.f, 0.f, 0.f};
      #pragma unroll
      for (int kt = 0; kt < 4; ++kt) {
        short8 bf = *(const short8*)(qkvF + (((h * 11 + 10) * 4 + kt) * 64 + lane) * 8);
        acc = __builtin_amdgcn_mfma_f32_16x16x32_bf16(Aq[kt], bf, acc, 0, 0, 0);
      }
      QKV_EPI(cl, acc);
    }
    __syncthreads();  // A: q/k/v ready
    // scores in registers: wave owns keys [wave*16, +16)
    f32x4 sc = {0.f, 0.f, 0.f, 0.f};
    #pragma unroll
    for (int kt = 0; kt < 2; ++kt) {
      short8 a = *(const short8*)&q_s[lrow * 72 + kt * 32 + lq * 8];
      short8 bk = *(const short8*)&kp_s[(wave * 16 + lrow) * 72 + kt * 32 + lq * 8];
      sc = __builtin_amdgcn_mfma_f32_16x16x32_bf16(a, bk, sc, 0, 0, 0);
    }
    // per-wave row-max over its 16 keys (16-lane shuffle groups)
    float mr[4] = {sc[0], sc[1], sc[2], sc[3]};
    #pragma unroll
    for (int off = 8; off; off >>= 1) {
      #pragma unroll
      for (int r = 0; r < 4; ++r) mr[r] = fmaxf(mr[r], __shfl_xor(mr[r], off, 16));
    }
    if (lrow < 4) pm_s[lq * 4 + lrow][wave] = mr[lrow];
    __syncthreads();  // B: partial maxes ready
    float er[4], sr[4];
    #pragma unroll
    for (int r = 0; r < 4; ++r) {
      int row = lq * 4 + r;
      float gm = fmaxf(fmaxf(pm_s[row][0], pm_s[row][1]),
                       fmaxf(pm_s[row][2], pm_s[row][3]));
      er[r] = __expf(sc[r] - gm);
      sr[r] = er[r];
    }
    #pragma unroll
    for (int off = 8; off; off >>= 1) {
      #pragma unroll
      for (int r = 0; r < 4; ++r) sr[r] += __shfl_xor(sr[r], off, 16);
    }
    if (lrow < 4) ps_s[lq * 4 + lrow][wave] = sr[lrow];
    // unnormalized P (bf16) into kp rows 0..15; normalize after PV
    #pragma unroll
    for (int r = 0; r < 4; ++r)
      kp_s[(lq * 4 + r) * 72 + wave * 16 + lrow] = f2bf(er[r]);
    __syncthreads();  // C: P + partial sums ready (k reads all done at B)
    // PV: wave owns out cols [wave*16, +16)
    {
      int col = wave * 16 + lrow;
      f32x4 ov = {0.f, 0.f, 0.f, 0.f};
      #pragma unroll
      for (int kt = 0; kt < 2; ++kt) {
        short8 a = *(const short8*)&kp_s[lrow * 72 + kt * 32 + lq * 8];
        short8 bv = *(const short8*)&vT_s[col * 72 + kt * 32 + lq * 8];
        ov = __builtin_amdgcn_mfma_f32_16x16x32_bf16(a, bv, ov, 0, 0, 0);
      }
      if (col < 56) {
        #pragma unroll
        for (int r = 0; r < 4; ++r) {
          int row = lq * 4 + r;
          float gs = ps_s[row][0] + ps_s[row][1] + ps_s[row][2] + ps_s[row][3];
          float o = ov[r] * (1.f / gs);
          size_t token = ((size_t)(b * 64 + nh * 4 + (row >> 2))) * 64 + (nw * 4 + (row & 3));
          o_bf[token * 224 + h * 56 + col] = f2bf(o);
        }
      }
    }
    __syncthreads();  // D: PV done before next head rewrites LDS
  }
#undef QKV_EPI
}

// ---------------------------- attn_proj GEMM + bias + residual into hs2
__global__ __launch_bounds__(256, 4) void aproj_kernel(
    const short* __restrict__ o_bf, const short* __restrict__ apF,
    const float* __restrict__ apb, float* __restrict__ hs2) {
  __shared__ alignas(16) short o_s[64 * 232];
  int blk = blockIdx.x;  // 512 x 64 tokens
  int tid = threadIdx.x;
  for (int e = tid; e < 64 * 28; e += 256) {
    int m = e / 28, c = e % 28;
    *(short8*)&o_s[m * 232 + c * 8] =
        *(const short8*)(o_bf + ((size_t)blk * 64 + m) * 224 + c * 8);
  }
  __syncthreads();
  int wave = tid >> 6, lane = tid & 63, lrow = lane & 15, lq = lane >> 4;
  short8 Ao[7];
  #pragma unroll
  for (int kt = 0; kt < 7; ++kt)
    Ao[kt] = *(const short8*)&o_s[(wave * 16 + lrow) * 232 + kt * 32 + lq * 8];
  for (int pr = 0; pr < 7; ++pr) {
    int c0 = pr * 32 + lrow, c1 = c0 + 16;
    f32x4 acc0 = {0.f, 0.f, 0.f, 0.f}, acc1 = {0.f, 0.f, 0.f, 0.f};
    #pragma unroll
    for (int kt = 0; kt < 7; ++kt) {
      short8 b0 = *(const short8*)(apF + (((2 * pr) * 7 + kt) * 64 + lane) * 8);
      short8 b1 = *(const short8*)(apF + (((2 * pr + 1) * 7 + kt) * 64 + lane) * 8);
      acc0 = __builtin_amdgcn_mfma_f32_16x16x32_bf16(Ao[kt], b0, acc0, 0, 0, 0);
      acc1 = __builtin_amdgcn_mfma_f32_16x16x32_bf16(Ao[kt], b1, acc1, 0, 0, 0);
    }
    float bi0 = apb[c0], bi1 = apb[c1];
    #pragma unroll
    for (int r = 0; r < 4; ++r) {
      size_t row = (size_t)blk * 64 + wave * 16 + lq * 4 + r;
      hs2[row * 224 + c0] += acc0[r] + bi0;
      hs2[row * 224 + c1] += acc1[r] + bi1;
    }
  }
}

// ------------- fused LN2 + mlp1(MFMA) + GELU + mlp2(MFMA) + residual
// 512 threads (8 waves), 32 tokens/block -> 16 waves/CU.
__global__ __launch_bounds__(512, 4) void mlp_kernel(
    const float* __restrict__ hs2, const float* __restrict__ g2,
    const float* __restrict__ b2, const short* __restrict__ m1F,
    const float* __restrict__ b1, const short* __restrict__ m2F,
    const float* __restrict__ b2b, float* __restrict__ out) {
  __shared__ alignas(16) short ln_s[32 * 232];   // 14848 B
  __shared__ alignas(16) short hid_s[32 * 904];  // 57856 B
  int blk = blockIdx.x;  // 1024 x 32 tokens
  int tid = threadIdx.x;
  size_t base = (size_t)blk * 32 * 224;
  // LN2 in registers: 16 lanes per row, one hs2 read
  {
    int row = tid >> 4, l = tid & 15;
    const float* rp = hs2 + base + (size_t)row * 224;
    float v[14];
    float s = 0.f;
    #pragma unroll
    for (int c = 0; c < 14; ++c) { v[c] = rp[l + 16 * c]; s += v[c]; }
    #pragma unroll
    for (int off = 8; off; off >>= 1) s += __shfl_xor(s, off, 16);
    float mean = s * (1.f / 224.f);
    float s2 = 0.f;
    #pragma unroll
    for (int c = 0; c < 14; ++c) { float d = v[c] - mean; s2 = fmaf(d, d, s2); }
    #pragma unroll
    for (int off = 8; off; off >>= 1) s2 += __shfl_xor(s2, off, 16);
    float rs = rsqrtf(s2 * (1.f / 224.f) + 1e-6f);
    #pragma unroll
    for (int c = 0; c < 14; ++c) {
      int cc = l + 16 * c;
      ln_s[row * 232 + cc] = f2bf((v[c] - mean) * rs * g2[cc] + b2[cc]);
    }
  }
  __syncthreads();
  int wave = tid >> 6, lane = tid & 63, lrow = lane & 15, lq = lane >> 4;
  short8 A[2][7];
  #pragma unroll
  for (int mt = 0; mt < 2; ++mt)
    #pragma unroll
    for (int kt = 0; kt < 7; ++kt)
      A[mt][kt] = *(const short8*)&ln_s[(mt * 16 + lrow) * 232 + kt * 32 + lq * 8];
  // GEMM1: wave owns 7 N-tiles = cols [wave*112, +112)
  for (int t = 0; t < 7; ++t) {
    int nt = wave * 7 + t;
    int c0 = nt * 16 + lrow;
    f32x4 a0 = {0.f, 0.f, 0.f, 0.f}, a1 = {0.f, 0.f, 0.f, 0.f};
    #pragma unroll
    for (int kt = 0; kt < 7; ++kt) {
      short8 bw = *(const short8*)(m1F + (((size_t)nt * 7 + kt) * 64 + lane) * 8);
      a0 = __builtin_amdgcn_mfma_f32_16x16x32_bf16(A[0][kt], bw, a0, 0, 0, 0);
      a1 = __builtin_amdgcn_mfma_f32_16x16x32_bf16(A[1][kt], bw, a1, 0, 0, 0);
    }
    float bi = b1[c0];
    #pragma unroll
    for (int r = 0; r < 4; ++r) {
      hid_s[(lq * 4 + r) * 904 + c0]      = f2bf(gelu_exact(a0[r] + bi));
      hid_s[(16 + lq * 4 + r) * 904 + c0] = f2bf(gelu_exact(a1[r] + bi));
    }
  }
  __syncthreads();
  // GEMM2: 14 N-tiles over 8 waves
  for (int t = wave; t < 14; t += 8) {
    int c0 = t * 16 + lrow;
    f32x4 a0 = {0.f, 0.f, 0.f, 0.f}, a1 = {0.f, 0.f, 0.f, 0.f};
    #pragma unroll 7
    for (int kt = 0; kt < 28; ++kt) {
      short8 x0 = *(const short8*)&hid_s[lrow * 904 + kt * 32 + lq * 8];
      short8 x1 = *(const short8*)&hid_s[(16 + lrow) * 904 + kt * 32 + lq * 8];
      short8 bw = *(const short8*)(m2F + (((size_t)t * 28 + kt) * 64 + lane) * 8);
      a0 = __builtin_amdgcn_mfma_f32_16x16x32_bf16(x0, bw, a0, 0, 0, 0);
      a1 = __builtin_amdgcn_mfma_f32_16x16x32_bf16(x1, bw, a1, 0, 0, 0);
    }
    float bi = b2b[c0];
    #pragma unroll
    for (int r = 0; r < 4; ++r) {
      size_t i0 = base + (size_t)(lq * 4 + r) * 224 + c0;
      size_t i1 = base + (size_t)(16 + lq * 4 + r) * 224 + c0;
      out[i0] = hs2[i0] + a0[r] + bi;
      out[i1] = hs2[i1] + a1[r] + bi;
    }
  }
}

extern "C" void kernel_launch(void* const* d_in, const int* in_sizes, int n_in,
                              void* d_out, int out_size, void* d_ws, size_t ws_size,
                              hipStream_t stream) {
  const float* x    = (const float*)d_in[0];
  const float* ln1g = (const float*)d_in[1];
  const float* ln1b = (const float*)d_in[2];
  const float* qkvw = (const float*)d_in[3];
  const float* qkvb = (const float*)d_in[4];
  const float* apw  = (const float*)d_in[5];
  const float* apb  = (const float*)d_in[6];
  const float* rpw  = (const float*)d_in[7];
  const float* rpb  = (const float*)d_in[8];
  const float* ln2g = (const float*)d_in[9];
  const float* ln2b = (const float*)d_in[10];
  const float* w1   = (const float*)d_in[11];
  const float* b1   = (const float*)d_in[12];
  const float* w2   = (const float*)d_in[13];
  const float* b2   = (const float*)d_in[14];
  float* out = (float*)d_out;

  short* hs_bf = (short*)d_ws;
  float* hs2   = (float*)((char*)d_ws + 29360128);
  short* o_bf  = (short*)((char*)d_ws + 58720256);
  short* wF    = (short*)((char*)d_ws + 73400320);

  cast_w_kernel<<<1024, 256, 0, stream>>>(qkvw, rpw, apw, w1, w2, wF);
  ln1_kernel<<<32768, 256, 0, stream>>>(x, ln1g, ln1b, hs_bf);
  respool_kernel<<<2048, 256, 0, stream>>>(hs_bf, wF + 90112, rpb, hs2);
  attn_kernel<<<2048, 256, 0, stream>>>(hs_bf, wF, qkvb, o_bf);
  aproj_kernel<<<512, 256, 0, stream>>>(o_bf, wF + 118784, apb, hs2);
  mlp_kernel<<<1024, 512, 0, stream>>>(hs2, ln2g, ln2b, wF + 168960, b1,
                                       wF + 369664, b2, out);
}